// Round 10
// baseline (332.058 us; speedup 1.0000x reference)
//
#include <hip/hip_runtime.h>
#include <hip/hip_bf16.h>
#include <math.h>

using bf16 = __hip_bfloat16;
typedef short bf16x8 __attribute__((ext_vector_type(8)));
typedef float f32x4 __attribute__((ext_vector_type(4)));

static constexpr int B = 2, S = 2048, D = 1024, H = 16, HD = 64, DFF = 4096;
static constexpr int NR = B * S;   // 4096 rows
static constexpr int DQ = 3072;    // packed QKV row stride
static constexpr float EPS = 1e-5f;

__device__ __forceinline__ bf16 f2b(float v) { return __float2bfloat16(v); }

// exact GELU via branchless A&S 7.1.26 erf (max abs err 1.5e-7 << bf16 rounding)
__device__ __forceinline__ float gelu_exact(float v) {
    const float u = v * 0.70710678118654752f;
    const float au = fabsf(u);
    const float t = __builtin_amdgcn_rcpf(1.0f + 0.3275911f * au);
    float poly = 1.061405429f;
    poly = poly * t - 1.453152027f;
    poly = poly * t + 1.421413741f;
    poly = poly * t - 0.284496736f;
    poly = poly * t + 0.254829592f;
    poly = poly * t;
    const float ea = 1.0f - poly * __expf(-u * u);
    return 0.5f * v * (1.0f + copysignf(ea, u));
}

// async global->LDS, 16B per lane; LDS dest must be wave-uniform base + lane*16
typedef __attribute__((address_space(1))) const void* gp1_t;
typedef __attribute__((address_space(3))) void* sp3_t;
__device__ __forceinline__ void gld_lds16(const bf16* g, bf16* l) {
    __builtin_amdgcn_global_load_lds((gp1_t)(const void*)g, (sp3_t)(void*)l, 16, 0, 0);
}

// ---------------- tiled transpose + fp32->bf16 body: dst[n][k] = src[k][n] ----------
__device__ __forceinline__ void convT_body(const float* __restrict__ src, // [K][N]
                                           bf16* __restrict__ dst,        // [N][K]
                                           int K, int N, int k0, int n0, int tid) {
    __shared__ float tile[64][65];
    const int r = tid >> 4, c = (tid & 15) * 4;
#pragma unroll
    for (int rr = 0; rr < 64; rr += 16) {
        float4 v = *(const float4*)&src[(size_t)(k0 + r + rr) * N + n0 + c];
        tile[r + rr][c] = v.x; tile[r + rr][c + 1] = v.y;
        tile[r + rr][c + 2] = v.z; tile[r + rr][c + 3] = v.w;
    }
    __syncthreads();
    const int n = tid >> 2, ks = (tid & 3) * 16;
    union { bf16 h[16]; int4 v2[2]; } o;
#pragma unroll
    for (int i = 0; i < 16; ++i) o.h[i] = f2b(tile[ks + i][n]);
    bf16* dp = &dst[(size_t)(n0 + n) * K + k0 + ks];
    *(int4*)dp = o.v2[0];
    *(int4*)(dp + 8) = o.v2[1];
}

__global__ __launch_bounds__(256) void convT_kernel(const float* __restrict__ src,
                                                    bf16* __restrict__ dst,
                                                    int K, int N) {
    convT_body(src, dst, K, N, blockIdx.x * 64, blockIdx.y * 64, threadIdx.x);
}

// ---------------- LayerNorm body: fp32 in, bf16 out; one block per row -----------
__device__ __forceinline__ void ln_body(const float* __restrict__ x,
                                        const float* __restrict__ g,
                                        const float* __restrict__ b,
                                        bf16* __restrict__ out, int row, int tid) {
    const float4 v4 = ((const float4*)(x + (size_t)row * D))[tid];
    float v[4] = {v4.x, v4.y, v4.z, v4.w};
    float s = v[0] + v[1] + v[2] + v[3];
    float sq = v[0] * v[0] + v[1] * v[1] + v[2] * v[2] + v[3] * v[3];
#pragma unroll
    for (int off = 32; off >= 1; off >>= 1) {
        s += __shfl_xor(s, off);
        sq += __shfl_xor(sq, off);
    }
    __shared__ float ssum[4], ssq[4];
    const int wave = tid >> 6;
    if ((tid & 63) == 0) { ssum[wave] = s; ssq[wave] = sq; }
    __syncthreads();
    s = ssum[0] + ssum[1] + ssum[2] + ssum[3];
    sq = ssq[0] + ssq[1] + ssq[2] + ssq[3];
    const float mu = s * (1.0f / D);
    const float var = sq * (1.0f / D) - mu * mu;
    const float rstd = rsqrtf(var + EPS);
    bf16* orow = out + (size_t)row * D;
#pragma unroll
    for (int i = 0; i < 4; ++i) {
        const int c = tid * 4 + i;
        orow[c] = f2b((v[i] - mu) * rstd * g[c] + b[c]);
    }
}

__global__ __launch_bounds__(256) void ln_kernel(const float* __restrict__ x,
                                                 const float* __restrict__ g,
                                                 const float* __restrict__ b,
                                                 bf16* __restrict__ out) {
    ln_body(x, g, b, out, blockIdx.x, threadIdx.x);
}

// prep: weight transposes + LN1 in ONE dispatch.
// blocks [0,768) Wq/Wk/Wv -> WqkvT, [768,1024) Wo, [1024,2048) W2,
// [2048,nW) W1 (wide only, nW=3072), [nW, nW+NR) LN1 rows.
__global__ __launch_bounds__(256) void prep_kernel(const float* __restrict__ Wq,
                                                   const float* __restrict__ Wk,
                                                   const float* __restrict__ Wv,
                                                   const float* __restrict__ Wo,
                                                   const float* __restrict__ W2,
                                                   const float* __restrict__ W1,
                                                   bf16* __restrict__ WqkvT,
                                                   bf16* __restrict__ WoT,
                                                   bf16* __restrict__ W2T,
                                                   bf16* __restrict__ W1T,
                                                   const float* __restrict__ x,
                                                   const float* __restrict__ ln1_g,
                                                   const float* __restrict__ ln1_b,
                                                   bf16* __restrict__ h,
                                                   int nW) {
    const int bid = blockIdx.x;
    const int tid = threadIdx.x;
    if (bid >= nW) { ln_body(x, ln1_g, ln1_b, h, bid - nW, tid); return; }
    const float* src;
    bf16* dst;
    int K, N, bx, by;
    if (bid < 768) {
        const int j = bid >> 8, r = bid & 255;
        src = (j == 0) ? Wq : ((j == 1) ? Wk : Wv);
        dst = WqkvT + (size_t)j * D * D;
        K = D; N = D; bx = r & 15; by = r >> 4;
    } else if (bid < 1024) {
        const int r = bid - 768;
        src = Wo; dst = WoT; K = D; N = D; bx = r & 15; by = r >> 4;
    } else if (bid < 2048) {
        const int r = bid - 1024;
        src = W2; dst = W2T; K = DFF; N = D; bx = r & 63; by = r >> 6;
    } else {
        const int r = bid - 2048;
        src = W1; dst = W1T; K = D; N = DFF; bx = r & 15; by = r >> 4;
    }
    convT_body(src, dst, K, N, bx * 64, by * 64, tid);
}

// ---------------- GEMM: C[M,N] = A[M,K] @ Bt[N,K]^T  (128x64 tile, 256 thr) -------
// Round-7 proven inner loop (BK=64, 16 MFMA/barrier, [row][32] ks-split LDS)
// + T4 counted waits: 3-buffer LDS ring, distance-2 prefetch, and
// `s_waitcnt vmcnt(6) lgkmcnt(0)` + raw s_barrier per K-tile — the next tile's
// 6 loads stay in flight ACROSS the barrier (never drained to 0 in the loop).
// lgkmcnt(0) before the barrier also guarantees no wave has pending ds_reads of
// the ring slot about to be overwritten (cross-wave WAR safety). 72 KB LDS ->
// 2 blocks/CU (rounds 1/2: this structure is occupancy-insensitive).
// EPI 0: bf16 out. EPI 1: fp32 + bias + fp32 residual (res==C in-place OK).
// EPI 2: bf16 out + fp32 bias + exact GELU.
template <int EPI, int BN>
__global__ __launch_bounds__(256) void gemm_bt(const bf16* __restrict__ A,
                                               const bf16* __restrict__ Bt,
                                               const float* __restrict__ bias,
                                               const float* __restrict__ res,
                                               void* __restrict__ Cv,
                                               int M, int N, int K) {
    constexpr int NTW = BN / 32;
    constexpr int AHALF = 128 * 32;           // elems per ks-half of A
    constexpr int BHALF = BN * 32;            // elems per ks-half of B
    constexpr int ASZ = 2 * AHALF, BSZ = 2 * BHALF;
    constexpr int RB = ASZ + BSZ;             // ring-buffer stride (elems)
    constexpr int CST = BN + 8;               // epilogue stage stride
    __shared__ __align__(16) bf16 smem[3 * RB];   // 72 KB at BN=64

    const int Mtiles = M / 128;
    const int p = blockIdx.x;
    const int tm = p % Mtiles;                // tm-fast: B panel reuse in L2
    const int tn = p / Mtiles;
    const int tid = threadIdx.x;
    const int wave = tid >> 6, lane = tid & 63;
    const int wm = wave >> 1, wn = wave & 1;
    const int quad = lane >> 4, l16 = lane & 15;

    // staging: thread t covers row r4 = t>>2, seg4 = (t&3)*8 within a ks-half.
    const int r4 = tid >> 2, s4 = (tid & 3) * 8;
    const size_t K64 = (size_t)64 * K;
    const int nk = K / 64;

    f32x4 acc[4][NTW];
#pragma unroll
    for (int i = 0; i < 4; ++i)
#pragma unroll
        for (int j = 0; j < NTW; ++j) acc[i][j] = (f32x4){0.f, 0.f, 0.f, 0.f};

    const bf16* Ap = A + (size_t)(tm * 128 + r4) * K + s4;
    const bf16* Bp = Bt + (size_t)(tn * BN + r4) * K + s4;

    auto stage = [&](const bf16* ap, const bf16* bp, int d) {
        bf16* base = smem + d * RB;
        gld_lds16(ap,            base + tid * 8);
        gld_lds16(ap + K64,      base + (256 + tid) * 8);
        gld_lds16(ap + 32,       base + (512 + tid) * 8);
        gld_lds16(ap + K64 + 32, base + (768 + tid) * 8);
        gld_lds16(bp,            base + ASZ + tid * 8);
        gld_lds16(bp + 32,       base + ASZ + (256 + tid) * 8);
    };

    // prologue: tiles 0,1 -> ring slots 0,1 (distance-2)
    stage(Ap, Bp, 0);
    stage(Ap + 64, Bp + 64, 1);
    Ap += 128;
    Bp += 128;

    int cur = 0;
    for (int kt = 0; kt < nk; ++kt) {
        // tile kt's 6 loads done; tile kt+1's 6 remain in flight across the barrier
        if (kt + 1 < nk) {
            asm volatile("s_waitcnt vmcnt(6) lgkmcnt(0)" ::: "memory");
        } else {
            asm volatile("s_waitcnt vmcnt(0) lgkmcnt(0)" ::: "memory");
        }
        __builtin_amdgcn_s_barrier();
        if (kt + 2 < nk) {
            int wb = cur + 2;
            if (wb >= 3) wb -= 3;
            stage(Ap, Bp, wb);
            Ap += 64;
            Bp += 64;
        }

        const bf16* Acur = smem + cur * RB;
        const bf16* Bcur = Acur + ASZ;
#pragma unroll
        for (int ks = 0; ks < 2; ++ks) {
            const bf16* Ah = Acur + ks * AHALF;
            const bf16* Bh = Bcur + ks * BHALF;
            bf16x8 aF[4], bF[NTW];
#pragma unroll
            for (int mt = 0; mt < 4; ++mt)
                aF[mt] = *(const bf16x8*)(Ah + (wm * 64 + mt * 16 + l16) * 32 + quad * 8);
#pragma unroll
            for (int nt = 0; nt < NTW; ++nt)
                bF[nt] = *(const bf16x8*)(Bh + (wn * (BN / 2) + nt * 16 + l16) * 32 + quad * 8);
#pragma unroll
            for (int mt = 0; mt < 4; ++mt)
#pragma unroll
                for (int nt = 0; nt < NTW; ++nt)
                    acc[mt][nt] = __builtin_amdgcn_mfma_f32_16x16x32_bf16(
                        aF[mt], bF[nt], acc[mt][nt], 0, 0, 0);
        }
        cur = (cur + 1 == 3) ? 0 : cur + 1;
    }

    if constexpr (EPI == 1) {
        // fp32 + bias + residual, direct stores
#pragma unroll
        for (int nt = 0; nt < NTW; ++nt) {
            const int col = tn * BN + wn * (BN / 2) + nt * 16 + l16;
            const float bv = bias[col];
#pragma unroll
            for (int mt = 0; mt < 4; ++mt) {
                const int row0 = tm * 128 + wm * 64 + mt * 16 + quad * 4;
#pragma unroll
                for (int j = 0; j < 4; ++j) {
                    const size_t idx = (size_t)(row0 + j) * N + col;
                    ((float*)Cv)[idx] = acc[mt][nt][j] + bv + res[idx];
                }
            }
        }
    } else {
        // EPI 0/2: bf16 out; stage full 128xBN tile in LDS (overlays k-loop smem)
        bf16* C = (bf16*)Cv;
        __syncthreads();   // all waves done with k-loop LDS (full drain here is fine)
#pragma unroll
        for (int nt = 0; nt < NTW; ++nt) {
            const int ccol = wn * (BN / 2) + nt * 16 + l16;
            float bv = 0.f;
            if (EPI == 2) bv = bias[tn * BN + ccol];
#pragma unroll
            for (int mt = 0; mt < 4; ++mt) {
                const int r0 = wm * 64 + mt * 16 + quad * 4;
#pragma unroll
                for (int j = 0; j < 4; ++j) {
                    float v = acc[mt][nt][j];
                    if (EPI == 2) v = gelu_exact(v + bv);
                    smem[(r0 + j) * CST + ccol] = f2b(v);
                }
            }
        }
        __syncthreads();
        // write-out: 128 x BN tile; int4 coalesced; BN=64 -> 4 per thread
        bf16* crow = C + (size_t)(tm * 128) * N + tn * BN;
#pragma unroll
        for (int i = 0; i < BN / 16; ++i) {
            const int gid = i * 256 + tid;
            const int row = gid / (BN / 8), c8 = gid % (BN / 8);
            const int4 val = *(const int4*)(smem + row * CST + c8 * 8);
            *(int4*)(crow + (size_t)row * N + c8 * 8) = val;
        }
    }
}

// ---------------- MFMA flash attention (causal), 4 blocks/CU, all co-resident ----
// round-4 structure (swapped-operand + permuted-key, in-register P) + T13 defer-max
__global__ __launch_bounds__(256) void fattn_kernel(const bf16* __restrict__ QKV,
                                                    bf16* __restrict__ ctx) {
    const int id = blockIdx.x;
    const int bh = id & 31;
    const int k = id >> 5;          // 0..31
    const int t = (k < 16) ? 31 - k : k - 16;
    const int b = bh >> 4, h = bh & (H - 1);
    const int tid = threadIdx.x;
    const int wave = tid >> 6, lane = tid & 63;
    const int quad = lane >> 4, l16 = lane & 15;
    const bf16* Qp = QKV + (size_t)b * S * DQ + h * HD;
    const bf16* Kp = Qp + D;
    const bf16* Vp = Qp + 2 * D;

    __shared__ __align__(16) bf16 Ks[2][64 * 64];  // [key][seg], seg-swizzled
    __shared__ __align__(16) bf16 Vt[2][64][72];   // [d][key]

    const int keyA = tid >> 3;
    const int sA = (keyA & 3) | ((keyA >> 1) & 4);
    const int dsA = ((tid & 7) ^ sA) * 8;
    const size_t K32 = (size_t)32 * DQ;

    const int q0 = t * 64;
    const bf16* qg = Qp + (size_t)(q0 + wave * 16 + l16) * DQ + quad * 8;
    union U8 { bf16 h[8]; bf16x8 v; };
    U8 uq0, uq1;
    uq0.v = *(const bf16x8*)(qg);
    uq1.v = *(const bf16x8*)(qg + 32);
#pragma unroll
    for (int i = 0; i < 8; ++i) {
        uq0.h[i] = f2b(__bfloat162float(uq0.h[i]) * 0.125f);
        uq1.h[i] = f2b(__bfloat162float(uq1.h[i]) * 0.125f);
    }
    const bf16x8 aQ0 = uq0.v;
    const bf16x8 aQ1 = uq1.v;

    const int kb = (l16 >> 2) * 8 + (l16 & 3);
    const int sQ = (l16 & 3) | (((l16 >> 2) & 1) << 2);
    const int ofs0 = kb * 64 + ((quad ^ sQ) * 8);
    const int ofs1 = kb * 64 + (((4 + quad) ^ sQ) * 8);

    f32x4 O[4];
#pragma unroll
    for (int nt = 0; nt < 4; ++nt) O[nt] = (f32x4){0.f, 0.f, 0.f, 0.f};
    float rowm = -3.0e38f, rowl = 0.f;

    gld_lds16(Kp + (size_t)keyA * DQ + dsA, Ks[0] + tid * 8);
    gld_lds16(Kp + K32 + (size_t)keyA * DQ + dsA, Ks[0] + (256 + tid) * 8);
    {
        const bf16* vg = Vp + (size_t)lane * DQ + wave * 16;
        U8 u0, u1;
        u0.v = *(const bf16x8*)vg;
        u1.v = *(const bf16x8*)(vg + 8);
#pragma unroll
        for (int i = 0; i < 8; ++i) {
            Vt[0][wave * 16 + i][lane] = u0.h[i];
            Vt[0][wave * 16 + 8 + i][lane] = u1.h[i];
        }
    }

    const int nch = t + 1;
    for (int c = 0; c < nch; ++c) {
        const int cur = c & 1, nxt = cur ^ 1;
        __syncthreads();
        U8 u0, u1;
        if (c + 1 < nch) {
            const bf16* kg = Kp + (size_t)((c + 1) * 64 + keyA) * DQ + dsA;
            gld_lds16(kg, Ks[nxt] + tid * 8);
            gld_lds16(kg + K32, Ks[nxt] + (256 + tid) * 8);
            const bf16* vg = Vp + (size_t)((c + 1) * 64 + lane) * DQ + wave * 16;
            u0.v = *(const bf16x8*)vg;
            u1.v = *(const bf16x8*)(vg + 8);
        }

        f32x4 sc[4];
        __builtin_amdgcn_s_setprio(1);
#pragma unroll
        for (int m = 0; m < 4; ++m) {
            const bf16* kr = Ks[cur] + (m & 1) * 256 + (m >> 1) * 2048;
            const bf16x8 bK0 = *(const bf16x8*)(kr + ofs0);
            const bf16x8 bK1 = *(const bf16x8*)(kr + ofs1);
            f32x4 z = (f32x4){0.f, 0.f, 0.f, 0.f};
            z = __builtin_amdgcn_mfma_f32_16x16x32_bf16(bK0, aQ0, z, 0, 0, 0);
            z = __builtin_amdgcn_mfma_f32_16x16x32_bf16(bK1, aQ1, z, 0, 0, 0);
            sc[m] = z;
        }
        __builtin_amdgcn_s_setprio(0);
        if (c == nch - 1) {
            const int qloc = wave * 16 + l16;
#pragma unroll
            for (int m = 0; m < 4; ++m) {
                const int kk = quad * 8 + (m & 1) * 4 + (m >> 1) * 32;
#pragma unroll
                for (int j = 0; j < 4; ++j)
                    if (kk + j > qloc) sc[m][j] = -3.0e38f;
            }
        }
        // online softmax, lane-local row (q = l16); reduce across quads only
        f32x4 mv;
#pragma unroll
        for (int j = 0; j < 4; ++j)
            mv[j] = fmaxf(fmaxf(sc[0][j], sc[1][j]), fmaxf(sc[2][j], sc[3][j]));
        float mx = fmaxf(fmaxf(mv[0], mv[1]), fmaxf(mv[2], mv[3]));
        mx = fmaxf(mx, __shfl_xor(mx, 16));
        mx = fmaxf(mx, __shfl_xor(mx, 32));
        // T13 defer-max: only rescale when some lane's max grew past rowm+8
        if (__any(mx > rowm + 8.0f)) {
            const float mn = fmaxf(rowm, mx);
            const float alq = __expf(rowm - mn);
            rowm = mn;
            rowl *= alq;
#pragma unroll
            for (int nt = 0; nt < 4; ++nt)
#pragma unroll
                for (int j = 0; j < 4; ++j) O[nt][j] *= alq;
        }
        float rs = 0.f;
#pragma unroll
        for (int m = 0; m < 4; ++m)
#pragma unroll
            for (int j = 0; j < 4; ++j) {
                sc[m][j] = __expf(sc[m][j] - rowm);
                rs += sc[m][j];
            }
        rs += __shfl_xor(rs, 16);
        rs += __shfl_xor(rs, 32);
        rowl += rs;

        U8 p0, p1;
#pragma unroll
        for (int j = 0; j < 4; ++j) {
            p0.h[j]     = f2b(sc[0][j]);
            p0.h[4 + j] = f2b(sc[1][j]);
            p1.h[j]     = f2b(sc[2][j]);
            p1.h[4 + j] = f2b(sc[3][j]);
        }
        __builtin_amdgcn_s_setprio(1);
#pragma unroll
        for (int nt = 0; nt < 4; ++nt) {
            const bf16x8 bV0 = *(const bf16x8*)&Vt[cur][nt * 16 + l16][quad * 8];
            const bf16x8 bV1 = *(const bf16x8*)&Vt[cur][nt * 16 + l16][32 + quad * 8];
            O[nt] = __builtin_amdgcn_mfma_f32_16x16x32_bf16(bV0, p0.v, O[nt], 0, 0, 0);
            O[nt] = __builtin_amdgcn_mfma_f32_16x16x32_bf16(bV1, p1.v, O[nt], 0, 0, 0);
        }
        __builtin_amdgcn_s_setprio(0);
        if (c + 1 < nch) {
#pragma unroll
            for (int i = 0; i < 8; ++i) {
                Vt[nxt][wave * 16 + i][lane] = u0.h[i];
                Vt[nxt][wave * 16 + 8 + i][lane] = u1.h[i];
            }
        }
    }

    const float rlq = 1.0f / rowl;
    bf16* crow = ctx + (size_t)b * S * D + h * HD + (size_t)(q0 + wave * 16 + l16) * D;
#pragma unroll
    for (int nt = 0; nt < 4; ++nt) {
        union { bf16 h[4]; int2 v; } o;
#pragma unroll
        for (int j = 0; j < 4; ++j) o.h[j] = f2b(O[nt][j] * rlq);
        *(int2*)(crow + nt * 16 + quad * 4) = o.v;
    }
}

// ---------------- launcher ----------------
extern "C" void kernel_launch(void* const* d_in, const int* in_sizes, int n_in,
                              void* d_out, int out_size, void* d_ws, size_t ws_size,
                              hipStream_t stream) {
    const float* x     = (const float*)d_in[0];
    const float* ln1_g = (const float*)d_in[1];
    const float* ln1_b = (const float*)d_in[2];
    const float* Wq    = (const float*)d_in[3];
    const float* Wk    = (const float*)d_in[4];
    const float* Wv    = (const float*)d_in[5];
    const float* Wo    = (const float*)d_in[6];
    const float* bo    = (const float*)d_in[7];
    const float* ln2_g = (const float*)d_in[8];
    const float* ln2_b = (const float*)d_in[9];
    const float* W1    = (const float*)d_in[10];
    const float* b1    = (const float*)d_in[11];
    const float* W2    = (const float*)d_in[12];
    const float* b2    = (const float*)d_in[13];
    float* out = (float*)d_out;

    // workspace (MB), lifetime-overlapped; base peak 64 MB (+8 if wide):
    //   [ 0, 8): h (LN1 out)            (fallback: -> W1T after QKV)
    //   [ 8,32): QKVb (packed, 24 MB)   \
    //   [32,40): ctx (attn out)          } -> hff [8,40) (32 MB)
    //   [40,48): h2 (LN2 out)
    //   [48,54): WqkvT   [54,56): WoT   [56,64): W2T   [64,72): W1T (wide)
    //   x2 (fp32 residual) lives in d_out; final GEMM reads it in-place.
    char* ws = (char*)d_ws;
    const size_t MB = (size_t)1 << 20;
    const bool wide = ws_size >= 72 * MB;
    bf16* h     = (bf16*)(ws + 0 * MB);
    bf16* QKVb  = (bf16*)(ws + 8 * MB);
    bf16* hff   = (bf16*)(ws + 8 * MB);
    bf16* ctx   = (bf16*)(ws + 32 * MB);
    bf16* h2    = (bf16*)(ws + 40 * MB);
    bf16* WqkvT = (bf16*)(ws + 48 * MB);
    bf16* WoT   = (bf16*)(ws + 54 * MB);
    bf16* W2T   = (bf16*)(ws + 56 * MB);
    bf16* W1T   = wide ? (bf16*)(ws + 64 * MB) : (bf16*)(ws + 0 * MB);

    // --- 0) weight transposes + LN1, one dispatch ---
    const int nW = wide ? 3072 : 2048;
    prep_kernel<<<nW + NR, 256, 0, stream>>>(
        Wq, Wk, Wv, Wo, W2, W1, WqkvT, WoT, W2T, W1T, x, ln1_g, ln1_b, h, nW);
    // --- 1) QKV = h @ [Wq|Wk|Wv]  BK=64 128x64 tiles, counted-vmcnt ring ---
    gemm_bt<0, 64><<<(NR / 128) * (DQ / 64), 256, 0, stream>>>(
        h, WqkvT, nullptr, nullptr, QKVb, NR, DQ, D);
    // fallback: h dead now -> W1T into [0,8)
    if (!wide) convT_kernel<<<dim3(16, 64), 256, 0, stream>>>(W1, W1T, D, DFF);
    // --- 2) flash attention -> ctx (1024 blocks, 4/CU, all co-resident) ---
    fattn_kernel<<<dim3((S / 64) * B * H), 256, 0, stream>>>(QKVb, ctx);
    // --- 3) x2 = x + ctx @ Wo + bo   (fp32 into d_out), 512 blocks ---
    gemm_bt<1, 64><<<(NR / 128) * (D / 64), 256, 0, stream>>>(
        ctx, WoT, bo, x, out, NR, D, D);
    // --- 4) LN2 ---
    ln_kernel<<<NR, 256, 0, stream>>>(out, ln2_g, ln2_b, h2);
    // --- 5) hff = gelu(h2 @ W1 + b1)  2048 blocks ---
    gemm_bt<2, 64><<<(NR / 128) * (DFF / 64), 256, 0, stream>>>(
        h2, W1T, b1, nullptr, hff, NR, DFF, D);
    // --- 6) out = x2 + hff @ W2 + b2   in-place ---
    gemm_bt<1, 64><<<(NR / 128) * (D / 64), 256, 0, stream>>>(
        hff, W2T, b2, out, out, NR, D, DFF);
}

// Round 11
// 318.956 us; speedup vs baseline: 1.0411x; 1.0411x over previous
//
#include <hip/hip_runtime.h>
#include <hip/hip_bf16.h>
#include <math.h>

using bf16 = __hip_bfloat16;
typedef short bf16x8 __attribute__((ext_vector_type(8)));
typedef float f32x4 __attribute__((ext_vector_type(4)));

static constexpr int B = 2, S = 2048, D = 1024, H = 16, HD = 64, DFF = 4096;
static constexpr int NR = B * S;   // 4096 rows
static constexpr int DQ = 3072;    // packed QKV row stride
static constexpr float EPS = 1e-5f;

__device__ __forceinline__ bf16 f2b(float v) { return __float2bfloat16(v); }

// exact GELU via branchless A&S 7.1.26 erf (max abs err 1.5e-7 << bf16 rounding)
__device__ __forceinline__ float gelu_exact(float v) {
    const float u = v * 0.70710678118654752f;
    const float au = fabsf(u);
    const float t = __builtin_amdgcn_rcpf(1.0f + 0.3275911f * au);
    float poly = 1.061405429f;
    poly = poly * t - 1.453152027f;
    poly = poly * t + 1.421413741f;
    poly = poly * t - 0.284496736f;
    poly = poly * t + 0.254829592f;
    poly = poly * t;
    const float ea = 1.0f - poly * __expf(-u * u);
    return 0.5f * v * (1.0f + copysignf(ea, u));
}

// async global->LDS, 16B per lane; LDS dest must be wave-uniform base + lane*16
typedef __attribute__((address_space(1))) const void* gp1_t;
typedef __attribute__((address_space(3))) void* sp3_t;
__device__ __forceinline__ void gld_lds16(const bf16* g, bf16* l) {
    __builtin_amdgcn_global_load_lds((gp1_t)(const void*)g, (sp3_t)(void*)l, 16, 0, 0);
}

// ---------------- tiled transpose + fp32->bf16 body: dst[n][k] = src[k][n] ----------
__device__ __forceinline__ void convT_body(const float* __restrict__ src, // [K][N]
                                           bf16* __restrict__ dst,        // [N][K]
                                           int K, int N, int k0, int n0, int tid) {
    __shared__ float tile[64][65];
    const int r = tid >> 4, c = (tid & 15) * 4;
#pragma unroll
    for (int rr = 0; rr < 64; rr += 16) {
        float4 v = *(const float4*)&src[(size_t)(k0 + r + rr) * N + n0 + c];
        tile[r + rr][c] = v.x; tile[r + rr][c + 1] = v.y;
        tile[r + rr][c + 2] = v.z; tile[r + rr][c + 3] = v.w;
    }
    __syncthreads();
    const int n = tid >> 2, ks = (tid & 3) * 16;
    union { bf16 h[16]; int4 v2[2]; } o;
#pragma unroll
    for (int i = 0; i < 16; ++i) o.h[i] = f2b(tile[ks + i][n]);
    bf16* dp = &dst[(size_t)(n0 + n) * K + k0 + ks];
    *(int4*)dp = o.v2[0];
    *(int4*)(dp + 8) = o.v2[1];
}

__global__ __launch_bounds__(256) void convT_kernel(const float* __restrict__ src,
                                                    bf16* __restrict__ dst,
                                                    int K, int N) {
    convT_body(src, dst, K, N, blockIdx.x * 64, blockIdx.y * 64, threadIdx.x);
}

// ---------------- LayerNorm body: fp32 in, bf16 out; one block per row -----------
__device__ __forceinline__ void ln_body(const float* __restrict__ x,
                                        const float* __restrict__ g,
                                        const float* __restrict__ b,
                                        bf16* __restrict__ out, int row, int tid) {
    const float4 v4 = ((const float4*)(x + (size_t)row * D))[tid];
    float v[4] = {v4.x, v4.y, v4.z, v4.w};
    float s = v[0] + v[1] + v[2] + v[3];
    float sq = v[0] * v[0] + v[1] * v[1] + v[2] * v[2] + v[3] * v[3];
#pragma unroll
    for (int off = 32; off >= 1; off >>= 1) {
        s += __shfl_xor(s, off);
        sq += __shfl_xor(sq, off);
    }
    __shared__ float ssum[4], ssq[4];
    const int wave = tid >> 6;
    if ((tid & 63) == 0) { ssum[wave] = s; ssq[wave] = sq; }
    __syncthreads();
    s = ssum[0] + ssum[1] + ssum[2] + ssum[3];
    sq = ssq[0] + ssq[1] + ssq[2] + ssq[3];
    const float mu = s * (1.0f / D);
    const float var = sq * (1.0f / D) - mu * mu;
    const float rstd = rsqrtf(var + EPS);
    bf16* orow = out + (size_t)row * D;
#pragma unroll
    for (int i = 0; i < 4; ++i) {
        const int c = tid * 4 + i;
        orow[c] = f2b((v[i] - mu) * rstd * g[c] + b[c]);
    }
}

__global__ __launch_bounds__(256) void ln_kernel(const float* __restrict__ x,
                                                 const float* __restrict__ g,
                                                 const float* __restrict__ b,
                                                 bf16* __restrict__ out) {
    ln_body(x, g, b, out, blockIdx.x, threadIdx.x);
}

// prep: weight transposes + LN1 in ONE dispatch.
// blocks [0,768) Wq/Wk/Wv -> WqkvT, [768,1024) Wo, [1024,2048) W2,
// [2048,nW) W1 (wide only, nW=3072), [nW, nW+NR) LN1 rows.
__global__ __launch_bounds__(256) void prep_kernel(const float* __restrict__ Wq,
                                                   const float* __restrict__ Wk,
                                                   const float* __restrict__ Wv,
                                                   const float* __restrict__ Wo,
                                                   const float* __restrict__ W2,
                                                   const float* __restrict__ W1,
                                                   bf16* __restrict__ WqkvT,
                                                   bf16* __restrict__ WoT,
                                                   bf16* __restrict__ W2T,
                                                   bf16* __restrict__ W1T,
                                                   const float* __restrict__ x,
                                                   const float* __restrict__ ln1_g,
                                                   const float* __restrict__ ln1_b,
                                                   bf16* __restrict__ h,
                                                   int nW) {
    const int bid = blockIdx.x;
    const int tid = threadIdx.x;
    if (bid >= nW) { ln_body(x, ln1_g, ln1_b, h, bid - nW, tid); return; }
    const float* src;
    bf16* dst;
    int K, N, bx, by;
    if (bid < 768) {
        const int j = bid >> 8, r = bid & 255;
        src = (j == 0) ? Wq : ((j == 1) ? Wk : Wv);
        dst = WqkvT + (size_t)j * D * D;
        K = D; N = D; bx = r & 15; by = r >> 4;
    } else if (bid < 1024) {
        const int r = bid - 768;
        src = Wo; dst = WoT; K = D; N = D; bx = r & 15; by = r >> 4;
    } else if (bid < 2048) {
        const int r = bid - 1024;
        src = W2; dst = W2T; K = DFF; N = D; bx = r & 63; by = r >> 6;
    } else {
        const int r = bid - 2048;
        src = W1; dst = W1T; K = D; N = DFF; bx = r & 15; by = r >> 4;
    }
    convT_body(src, dst, K, N, bx * 64, by * 64, tid);
}

// ---------------- GEMM: C[M,N] = A[M,K] @ Bt[N,K]^T  (128x64 tile, 256 thr) -------
// Round-9 proven structure (320 us config): BK=64 = 16 MFMAs per barrier; LDS
// double-buffer, distance-1 prefetch, [row][32] ks-split layout (conflict-free).
// 48 KB LDS -> 3 blocks/CU co-resident. Counted-vmcnt ring (r10) REGRESSED —
// do not reintroduce without the full 8-phase combo.
// EPI 0: bf16 out (LDS-staged int4 stores).
// EPI 1: fp32 + bias + fp32 residual (res==C in-place OK); residual PREFETCHED
//        at kt==nk-2 into regs (one k-tile ~1000cy of flight covers HBM latency,
//        epilogue tail becomes pure FMA+store). LDS binds occupancy, so the
//        +32 VGPR are free.
// EPI 2: bf16 out + fp32 bias + exact GELU (fast poly erf, LDS-staged).
template <int EPI, int BN>
__global__ __launch_bounds__(256) void gemm_bt(const bf16* __restrict__ A,
                                               const bf16* __restrict__ Bt,
                                               const float* __restrict__ bias,
                                               const float* __restrict__ res,
                                               void* __restrict__ Cv,
                                               int M, int N, int K) {
    constexpr int NTW = BN / 32;
    constexpr int AHALF = 128 * 32;           // elems per ks-half of A
    constexpr int BHALF = BN * 32;            // elems per ks-half of B
    constexpr int ASZ = 2 * AHALF, BSZ = 2 * BHALF;
    constexpr int CST = BN + 8;               // epilogue stage stride
    __shared__ __align__(16) bf16 smem[2 * (ASZ + BSZ)];   // 48 KB at BN=64

    const int Mtiles = M / 128;
    const int p = blockIdx.x;
    const int tm = p % Mtiles;                // tm-fast: B panel reuse in L2
    const int tn = p / Mtiles;
    const int tid = threadIdx.x;
    const int wave = tid >> 6, lane = tid & 63;
    const int wm = wave >> 1, wn = wave & 1;
    const int quad = lane >> 4, l16 = lane & 15;

    // staging: thread t covers row r4 = t>>2, seg4 = (t&3)*8 within a ks-half.
    const int r4 = tid >> 2, s4 = (tid & 3) * 8;
    const size_t K64 = (size_t)64 * K;
    const int nk = K / 64;

    f32x4 acc[4][NTW];
#pragma unroll
    for (int i = 0; i < 4; ++i)
#pragma unroll
        for (int j = 0; j < NTW; ++j) acc[i][j] = (f32x4){0.f, 0.f, 0.f, 0.f};

    const bf16* Ap = A + (size_t)(tm * 128 + r4) * K + s4;
    const bf16* Bp = Bt + (size_t)(tn * BN + r4) * K + s4;

    // prologue: K-tile 0 -> buf 0
    gld_lds16(Ap, smem + tid * 8);
    gld_lds16(Ap + K64, smem + (256 + tid) * 8);
    gld_lds16(Ap + 32, smem + (512 + tid) * 8);
    gld_lds16(Ap + K64 + 32, smem + (768 + tid) * 8);
    gld_lds16(Bp, smem + 2 * ASZ + tid * 8);
    gld_lds16(Bp + 32, smem + 2 * ASZ + (256 + tid) * 8);
    Ap += 64;
    Bp += 64;

    float rv[4][NTW][4];   // EPI1 residual prefetch (regs; unused otherwise)

    for (int kt = 0; kt < nk; ++kt) {
        const int cur = kt & 1, nxt = cur ^ 1;
        bf16* Acur = smem + cur * ASZ;
        bf16* Bcur = smem + 2 * ASZ + cur * BSZ;
        __syncthreads();
        if (kt + 1 < nk) {
            bf16* Anxt = smem + nxt * ASZ;
            bf16* Bnxt = smem + 2 * ASZ + nxt * BSZ;
            gld_lds16(Ap, Anxt + tid * 8);
            gld_lds16(Ap + K64, Anxt + (256 + tid) * 8);
            gld_lds16(Ap + 32, Anxt + (512 + tid) * 8);
            gld_lds16(Ap + K64 + 32, Anxt + (768 + tid) * 8);
            gld_lds16(Bp, Bnxt + tid * 8);
            gld_lds16(Bp + 32, Bnxt + (256 + tid) * 8);
            Ap += 64;
            Bp += 64;
        }

        if constexpr (EPI == 1) {
            // issue residual loads one k-tile early; they drain at the next
            // barrier's vmcnt(0) after ~1000cy of flight (>= HBM latency).
            if (kt == nk - 2) {
#pragma unroll
                for (int nt = 0; nt < NTW; ++nt) {
                    const int col = tn * BN + wn * (BN / 2) + nt * 16 + l16;
#pragma unroll
                    for (int mt = 0; mt < 4; ++mt) {
                        const int row0 = tm * 128 + wm * 64 + mt * 16 + quad * 4;
#pragma unroll
                        for (int j = 0; j < 4; ++j)
                            rv[mt][nt][j] = res[(size_t)(row0 + j) * N + col];
                    }
                }
            }
        }

#pragma unroll
        for (int ks = 0; ks < 2; ++ks) {
            const bf16* Ah = Acur + ks * AHALF;
            const bf16* Bh = Bcur + ks * BHALF;
            bf16x8 aF[4], bF[NTW];
#pragma unroll
            for (int mt = 0; mt < 4; ++mt)
                aF[mt] = *(const bf16x8*)(Ah + (wm * 64 + mt * 16 + l16) * 32 + quad * 8);
#pragma unroll
            for (int nt = 0; nt < NTW; ++nt)
                bF[nt] = *(const bf16x8*)(Bh + (wn * (BN / 2) + nt * 16 + l16) * 32 + quad * 8);
#pragma unroll
            for (int mt = 0; mt < 4; ++mt)
#pragma unroll
                for (int nt = 0; nt < NTW; ++nt)
                    acc[mt][nt] = __builtin_amdgcn_mfma_f32_16x16x32_bf16(
                        aF[mt], bF[nt], acc[mt][nt], 0, 0, 0);
        }
    }

    if constexpr (EPI == 1) {
        // fp32 + bias + prefetched residual, direct stores
#pragma unroll
        for (int nt = 0; nt < NTW; ++nt) {
            const int col = tn * BN + wn * (BN / 2) + nt * 16 + l16;
            const float bv = bias[col];
#pragma unroll
            for (int mt = 0; mt < 4; ++mt) {
                const int row0 = tm * 128 + wm * 64 + mt * 16 + quad * 4;
#pragma unroll
                for (int j = 0; j < 4; ++j) {
                    const size_t idx = (size_t)(row0 + j) * N + col;
                    ((float*)Cv)[idx] = acc[mt][nt][j] + bv + rv[mt][nt][j];
                }
            }
        }
    } else {
        // EPI 0/2: bf16 out; stage full 128xBN tile in LDS (overlays k-loop smem)
        bf16* C = (bf16*)Cv;
        __syncthreads();   // all waves done reading k-loop buffers
#pragma unroll
        for (int nt = 0; nt < NTW; ++nt) {
            const int ccol = wn * (BN / 2) + nt * 16 + l16;
            float bv = 0.f;
            if (EPI == 2) bv = bias[tn * BN + ccol];
#pragma unroll
            for (int mt = 0; mt < 4; ++mt) {
                const int r0 = wm * 64 + mt * 16 + quad * 4;
#pragma unroll
                for (int j = 0; j < 4; ++j) {
                    float v = acc[mt][nt][j];
                    if (EPI == 2) v = gelu_exact(v + bv);
                    smem[(r0 + j) * CST + ccol] = f2b(v);
                }
            }
        }
        __syncthreads();
        // write-out: 128 x BN tile = 128*(BN/8) int4; BN=64 -> 4 per thread
        bf16* crow = C + (size_t)(tm * 128) * N + tn * BN;
#pragma unroll
        for (int i = 0; i < BN / 16; ++i) {
            const int gid = i * 256 + tid;
            const int row = gid / (BN / 8), c8 = gid % (BN / 8);
            const int4 val = *(const int4*)(smem + row * CST + c8 * 8);
            *(int4*)(crow + (size_t)row * N + c8 * 8) = val;
        }
    }
}

// ---------------- MFMA flash attention (causal), 4 blocks/CU, all co-resident ----
// round-4 structure (swapped-operand + permuted-key, in-register P) + T13 defer-max
__global__ __launch_bounds__(256) void fattn_kernel(const bf16* __restrict__ QKV,
                                                    bf16* __restrict__ ctx) {
    const int id = blockIdx.x;
    const int bh = id & 31;
    const int k = id >> 5;          // 0..31
    const int t = (k < 16) ? 31 - k : k - 16;
    const int b = bh >> 4, h = bh & (H - 1);
    const int tid = threadIdx.x;
    const int wave = tid >> 6, lane = tid & 63;
    const int quad = lane >> 4, l16 = lane & 15;
    const bf16* Qp = QKV + (size_t)b * S * DQ + h * HD;
    const bf16* Kp = Qp + D;
    const bf16* Vp = Qp + 2 * D;

    __shared__ __align__(16) bf16 Ks[2][64 * 64];  // [key][seg], seg-swizzled
    __shared__ __align__(16) bf16 Vt[2][64][72];   // [d][key]

    const int keyA = tid >> 3;
    const int sA = (keyA & 3) | ((keyA >> 1) & 4);
    const int dsA = ((tid & 7) ^ sA) * 8;
    const size_t K32 = (size_t)32 * DQ;

    const int q0 = t * 64;
    const bf16* qg = Qp + (size_t)(q0 + wave * 16 + l16) * DQ + quad * 8;
    union U8 { bf16 h[8]; bf16x8 v; };
    U8 uq0, uq1;
    uq0.v = *(const bf16x8*)(qg);
    uq1.v = *(const bf16x8*)(qg + 32);
#pragma unroll
    for (int i = 0; i < 8; ++i) {
        uq0.h[i] = f2b(__bfloat162float(uq0.h[i]) * 0.125f);
        uq1.h[i] = f2b(__bfloat162float(uq1.h[i]) * 0.125f);
    }
    const bf16x8 aQ0 = uq0.v;
    const bf16x8 aQ1 = uq1.v;

    const int kb = (l16 >> 2) * 8 + (l16 & 3);
    const int sQ = (l16 & 3) | (((l16 >> 2) & 1) << 2);
    const int ofs0 = kb * 64 + ((quad ^ sQ) * 8);
    const int ofs1 = kb * 64 + (((4 + quad) ^ sQ) * 8);

    f32x4 O[4];
#pragma unroll
    for (int nt = 0; nt < 4; ++nt) O[nt] = (f32x4){0.f, 0.f, 0.f, 0.f};
    float rowm = -3.0e38f, rowl = 0.f;

    gld_lds16(Kp + (size_t)keyA * DQ + dsA, Ks[0] + tid * 8);
    gld_lds16(Kp + K32 + (size_t)keyA * DQ + dsA, Ks[0] + (256 + tid) * 8);
    {
        const bf16* vg = Vp + (size_t)lane * DQ + wave * 16;
        U8 u0, u1;
        u0.v = *(const bf16x8*)vg;
        u1.v = *(const bf16x8*)(vg + 8);
#pragma unroll
        for (int i = 0; i < 8; ++i) {
            Vt[0][wave * 16 + i][lane] = u0.h[i];
            Vt[0][wave * 16 + 8 + i][lane] = u1.h[i];
        }
    }

    const int nch = t + 1;
    for (int c = 0; c < nch; ++c) {
        const int cur = c & 1, nxt = cur ^ 1;
        __syncthreads();
        U8 u0, u1;
        if (c + 1 < nch) {
            const bf16* kg = Kp + (size_t)((c + 1) * 64 + keyA) * DQ + dsA;
            gld_lds16(kg, Ks[nxt] + tid * 8);
            gld_lds16(kg + K32, Ks[nxt] + (256 + tid) * 8);
            const bf16* vg = Vp + (size_t)((c + 1) * 64 + lane) * DQ + wave * 16;
            u0.v = *(const bf16x8*)vg;
            u1.v = *(const bf16x8*)(vg + 8);
        }

        f32x4 sc[4];
        __builtin_amdgcn_s_setprio(1);
#pragma unroll
        for (int m = 0; m < 4; ++m) {
            const bf16* kr = Ks[cur] + (m & 1) * 256 + (m >> 1) * 2048;
            const bf16x8 bK0 = *(const bf16x8*)(kr + ofs0);
            const bf16x8 bK1 = *(const bf16x8*)(kr + ofs1);
            f32x4 z = (f32x4){0.f, 0.f, 0.f, 0.f};
            z = __builtin_amdgcn_mfma_f32_16x16x32_bf16(bK0, aQ0, z, 0, 0, 0);
            z = __builtin_amdgcn_mfma_f32_16x16x32_bf16(bK1, aQ1, z, 0, 0, 0);
            sc[m] = z;
        }
        __builtin_amdgcn_s_setprio(0);
        if (c == nch - 1) {
            const int qloc = wave * 16 + l16;
#pragma unroll
            for (int m = 0; m < 4; ++m) {
                const int kk = quad * 8 + (m & 1) * 4 + (m >> 1) * 32;
#pragma unroll
                for (int j = 0; j < 4; ++j)
                    if (kk + j > qloc) sc[m][j] = -3.0e38f;
            }
        }
        // online softmax, lane-local row (q = l16); reduce across quads only
        f32x4 mv;
#pragma unroll
        for (int j = 0; j < 4; ++j)
            mv[j] = fmaxf(fmaxf(sc[0][j], sc[1][j]), fmaxf(sc[2][j], sc[3][j]));
        float mx = fmaxf(fmaxf(mv[0], mv[1]), fmaxf(mv[2], mv[3]));
        mx = fmaxf(mx, __shfl_xor(mx, 16));
        mx = fmaxf(mx, __shfl_xor(mx, 32));
        // T13 defer-max: only rescale when some lane's max grew past rowm+8
        if (__any(mx > rowm + 8.0f)) {
            const float mn = fmaxf(rowm, mx);
            const float alq = __expf(rowm - mn);
            rowm = mn;
            rowl *= alq;
#pragma unroll
            for (int nt = 0; nt < 4; ++nt)
#pragma unroll
                for (int j = 0; j < 4; ++j) O[nt][j] *= alq;
        }
        float rs = 0.f;
#pragma unroll
        for (int m = 0; m < 4; ++m)
#pragma unroll
            for (int j = 0; j < 4; ++j) {
                sc[m][j] = __expf(sc[m][j] - rowm);
                rs += sc[m][j];
            }
        rs += __shfl_xor(rs, 16);
        rs += __shfl_xor(rs, 32);
        rowl += rs;

        U8 p0, p1;
#pragma unroll
        for (int j = 0; j < 4; ++j) {
            p0.h[j]     = f2b(sc[0][j]);
            p0.h[4 + j] = f2b(sc[1][j]);
            p1.h[j]     = f2b(sc[2][j]);
            p1.h[4 + j] = f2b(sc[3][j]);
        }
        __builtin_amdgcn_s_setprio(1);
#pragma unroll
        for (int nt = 0; nt < 4; ++nt) {
            const bf16x8 bV0 = *(const bf16x8*)&Vt[cur][nt * 16 + l16][quad * 8];
            const bf16x8 bV1 = *(const bf16x8*)&Vt[cur][nt * 16 + l16][32 + quad * 8];
            O[nt] = __builtin_amdgcn_mfma_f32_16x16x32_bf16(bV0, p0.v, O[nt], 0, 0, 0);
            O[nt] = __builtin_amdgcn_mfma_f32_16x16x32_bf16(bV1, p1.v, O[nt], 0, 0, 0);
        }
        __builtin_amdgcn_s_setprio(0);
        if (c + 1 < nch) {
#pragma unroll
            for (int i = 0; i < 8; ++i) {
                Vt[nxt][wave * 16 + i][lane] = u0.h[i];
                Vt[nxt][wave * 16 + 8 + i][lane] = u1.h[i];
            }
        }
    }

    const float rlq = 1.0f / rowl;
    bf16* crow = ctx + (size_t)b * S * D + h * HD + (size_t)(q0 + wave * 16 + l16) * D;
#pragma unroll
    for (int nt = 0; nt < 4; ++nt) {
        union { bf16 h[4]; int2 v; } o;
#pragma unroll
        for (int j = 0; j < 4; ++j) o.h[j] = f2b(O[nt][j] * rlq);
        *(int2*)(crow + nt * 16 + quad * 4) = o.v;
    }
}

// ---------------- launcher ----------------
extern "C" void kernel_launch(void* const* d_in, const int* in_sizes, int n_in,
                              void* d_out, int out_size, void* d_ws, size_t ws_size,
                              hipStream_t stream) {
    const float* x     = (const float*)d_in[0];
    const float* ln1_g = (const float*)d_in[1];
    const float* ln1_b = (const float*)d_in[2];
    const float* Wq    = (const float*)d_in[3];
    const float* Wk    = (const float*)d_in[4];
    const float* Wv    = (const float*)d_in[5];
    const float* Wo    = (const float*)d_in[6];
    const float* bo    = (const float*)d_in[7];
    const float* ln2_g = (const float*)d_in[8];
    const float* ln2_b = (const float*)d_in[9];
    const float* W1    = (const float*)d_in[10];
    const float* b1    = (const float*)d_in[11];
    const float* W2    = (const float*)d_in[12];
    const float* b2    = (const float*)d_in[13];
    float* out = (float*)d_out;

    // workspace (MB), lifetime-overlapped; base peak 64 MB (+8 if wide):
    //   [ 0, 8): h (LN1 out)            (fallback: -> W1T after QKV)
    //   [ 8,32): QKVb (packed, 24 MB)   \
    //   [32,40): ctx (attn out)          } -> hff [8,40) (32 MB)
    //   [40,48): h2 (LN2 out)
    //   [48,54): WqkvT   [54,56): WoT   [56,64): W2T   [64,72): W1T (wide)
    //   x2 (fp32 residual) lives in d_out; final GEMM reads it in-place.
    char* ws = (char*)d_ws;
    const size_t MB = (size_t)1 << 20;
    const bool wide = ws_size >= 72 * MB;
    bf16* h     = (bf16*)(ws + 0 * MB);
    bf16* QKVb  = (bf16*)(ws + 8 * MB);
    bf16* hff   = (bf16*)(ws + 8 * MB);
    bf16* ctx   = (bf16*)(ws + 32 * MB);
    bf16* h2    = (bf16*)(ws + 40 * MB);
    bf16* WqkvT = (bf16*)(ws + 48 * MB);
    bf16* WoT   = (bf16*)(ws + 54 * MB);
    bf16* W2T   = (bf16*)(ws + 56 * MB);
    bf16* W1T   = wide ? (bf16*)(ws + 64 * MB) : (bf16*)(ws + 0 * MB);

    // --- 0) weight transposes + LN1, one dispatch ---
    const int nW = wide ? 3072 : 2048;
    prep_kernel<<<nW + NR, 256, 0, stream>>>(
        Wq, Wk, Wv, Wo, W2, W1, WqkvT, WoT, W2T, W1T, x, ln1_g, ln1_b, h, nW);
    // --- 1) QKV = h @ [Wq|Wk|Wv]  BK=64 128x64 tiles, 1536 blocks ---
    gemm_bt<0, 64><<<(NR / 128) * (DQ / 64), 256, 0, stream>>>(
        h, WqkvT, nullptr, nullptr, QKVb, NR, DQ, D);
    // fallback: h dead now -> W1T into [0,8)
    if (!wide) convT_kernel<<<dim3(16, 64), 256, 0, stream>>>(W1, W1T, D, DFF);
    // --- 2) flash attention -> ctx (1024 blocks, 4/CU, all co-resident) ---
    fattn_kernel<<<dim3((S / 64) * B * H), 256, 0, stream>>>(QKVb, ctx);
    // --- 3) x2 = x + ctx @ Wo + bo   (fp32 into d_out), 512 blocks ---
    gemm_bt<1, 64><<<(NR / 128) * (D / 64), 256, 0, stream>>>(
        ctx, WoT, bo, x, out, NR, D, D);
    // --- 4) LN2 ---
    ln_kernel<<<NR, 256, 0, stream>>>(out, ln2_g, ln2_b, h2);
    // --- 5) hff = gelu(h2 @ W1 + b1)  2048 blocks ---
    gemm_bt<2, 64><<<(NR / 128) * (DFF / 64), 256, 0, stream>>>(
        h2, W1T, b1, nullptr, hff, NR, DFF, D);
    // --- 6) out = x2 + hff @ W2 + b2   in-place ---
    gemm_bt<1, 64><<<(NR / 128) * (D / 64), 256, 0, stream>>>(
        hff, W2T, b2, out, out, NR, D, DFF);
}